// Round 2
// baseline (725.863 us; speedup 1.0000x reference)
//
#include <hip/hip_runtime.h>

// Problem constants (from reference): B=4096, N_GEN=512, F_GEN=64, EMB=16
#define N_GEN 512
#define F_GEN 64
#define EMB   16

// One block per batch row b. 512 threads, thread t handles node n = t.
// x row per block = 512*64*4B = 128 KB streamed once; all other operands are
// wave-uniform (scalar-cached) or tiny.
__launch_bounds__(512, 4)
__global__ void fused_policy_value_kernel(
    const float* __restrict__ x,      // [B, N, F]
    const float* __restrict__ Wg,     // [F, E] row-major
    const float* __restrict__ bg,     // [E]
    const float* __restrict__ Wv,     // [N*E, 1]
    const float* __restrict__ bv,     // [1]
    const float* __restrict__ param,  // [2]
    const float* __restrict__ high,   // [N]
    float* __restrict__ out)          // [B, 2N+1]
{
    const int b = blockIdx.x;
    const int t = threadIdx.x;        // == node index n

    float* orow = out + (size_t)b * (2 * N_GEN + 1);

    // ---- action head (batch-constant, recomputed per row) ----
    // sigmoid(param[i]); param is wave-uniform -> scalar loads
    const float p0 = param[0];
    const float p1 = param[1];
    const float s0 = 1.0f / (1.0f + __expf(-p0));
    const float s1 = 1.0f / (1.0f + __expf(-p1));
    const float h  = high[t];
    orow[2 * t]     = s0 * h;
    orow[2 * t + 1] = s1 * (h * 0.5f);

    // ---- embedder: emb[e] = relu(sum_f x[b,n,f] * Wg[f,e] + bg[e]) ----
    float acc[EMB];
    #pragma unroll
    for (int e = 0; e < EMB; ++e) acc[e] = bg[e];   // uniform -> s_load

    const float4* __restrict__ xr =
        reinterpret_cast<const float4*>(x + ((size_t)b * N_GEN + t) * F_GEN);

    #pragma unroll
    for (int ff = 0; ff < F_GEN / 4; ++ff) {
        const float4 v = xr[ff];
        const float xv[4] = {v.x, v.y, v.z, v.w};
        #pragma unroll
        for (int c = 0; c < 4; ++c) {
            // Wg row is wave-uniform -> scalar loads, FMA takes SGPR operand
            const float* __restrict__ wrow = Wg + (ff * 4 + c) * EMB;
            #pragma unroll
            for (int e = 0; e < EMB; ++e)
                acc[e] = fmaf(xv[c], wrow[e], acc[e]);
        }
    }

    // ---- value head partial: sum_e relu(acc[e]) * Wv[n*16+e] ----
    const float4* __restrict__ wv4 =
        reinterpret_cast<const float4*>(Wv + (size_t)t * EMB);
    float vp = 0.0f;
    #pragma unroll
    for (int q = 0; q < EMB / 4; ++q) {
        const float4 w = wv4[q];
        vp = fmaf(fmaxf(acc[q * 4 + 0], 0.0f), w.x, vp);
        vp = fmaf(fmaxf(acc[q * 4 + 1], 0.0f), w.y, vp);
        vp = fmaf(fmaxf(acc[q * 4 + 2], 0.0f), w.z, vp);
        vp = fmaf(fmaxf(acc[q * 4 + 3], 0.0f), w.w, vp);
    }

    // ---- block reduction over 512 threads (8 waves of 64) ----
    #pragma unroll
    for (int off = 32; off > 0; off >>= 1)
        vp += __shfl_down(vp, off, 64);

    __shared__ float red[8];
    const int wave = t >> 6;
    const int lane = t & 63;
    if (lane == 0) red[wave] = vp;
    __syncthreads();
    if (t == 0) {
        float s = 0.0f;
        #pragma unroll
        for (int w = 0; w < 8; ++w) s += red[w];
        orow[2 * N_GEN] = s + bv[0];   // val goes in the last column
    }
}

extern "C" void kernel_launch(void* const* d_in, const int* in_sizes, int n_in,
                              void* d_out, int out_size, void* d_ws, size_t ws_size,
                              hipStream_t stream) {
    const float* x     = (const float*)d_in[0];  // [B, N, F]
    const float* Wg    = (const float*)d_in[1];  // [F, E]
    const float* bg    = (const float*)d_in[2];  // [E]
    const float* Wv    = (const float*)d_in[3];  // [N*E, 1]
    const float* bv    = (const float*)d_in[4];  // [1]
    const float* param = (const float*)d_in[5];  // [2]
    const float* high  = (const float*)d_in[6];  // [N]
    float* out = (float*)d_out;                  // [B, 2N+1]

    const int B = in_sizes[0] / (N_GEN * F_GEN); // 4096

    fused_policy_value_kernel<<<B, N_GEN, 0, stream>>>(
        x, Wg, bg, Wv, bv, param, high, out);
}

// Round 3
// 720.047 us; speedup vs baseline: 1.0081x; 1.0081x over previous
//
#include <hip/hip_runtime.h>

// Problem constants (from reference): B=4096, N_GEN=512, F_GEN=64, EMB=16
#define N_GEN 512
#define F_GEN 64
#define EMB   16

// One block per batch row b. 512 threads, thread t handles node n = t.
// x row per block = 512*64*4B = 128 KB streamed once; HBM lines fully
// consumed (each thread reads 4 full 64B lines). W_gen/b_gen/param are
// wave-uniform -> scalar loads; W_val/high are L2-resident.
// ff loop chunked (#pragma unroll 4) to cap VGPR pressure well under the
// 128-VGPR limit implied by __launch_bounds__(512,4) -> no scratch spills.
__launch_bounds__(512, 4)
__global__ void fused_policy_value_kernel(
    const float* __restrict__ x,      // [B, N, F]
    const float* __restrict__ Wg,     // [F, E] row-major
    const float* __restrict__ bg,     // [E]
    const float* __restrict__ Wv,     // [N*E, 1]
    const float* __restrict__ bv,     // [1]
    const float* __restrict__ param,  // [2]
    const float* __restrict__ high,   // [N]
    float* __restrict__ out)          // [B, 2N+1]
{
    const int b = blockIdx.x;
    const int t = threadIdx.x;        // == node index n

    float* orow = out + (size_t)b * (2 * N_GEN + 1);

    // ---- action head (batch-constant, recomputed per row) ----
    const float p0 = param[0];
    const float p1 = param[1];
    const float s0 = 1.0f / (1.0f + __expf(-p0));
    const float s1 = 1.0f / (1.0f + __expf(-p1));
    const float h  = high[t];
    // NOTE: row stride 1025 floats is odd -> orow is only 4B-aligned for odd
    // b, so a float2 store would be misaligned. Keep two dword stores; the
    // two instructions cover complementary halves of the same lines and L2
    // write-combines them.
    orow[2 * t]     = s0 * h;
    orow[2 * t + 1] = s1 * (h * 0.5f);

    // ---- embedder: emb[e] = relu(sum_f x[b,n,f] * Wg[f,e] + bg[e]) ----
    float acc[EMB];
    #pragma unroll
    for (int e = 0; e < EMB; ++e) acc[e] = bg[e];   // uniform -> s_load

    const float4* __restrict__ xr =
        reinterpret_cast<const float4*>(x + ((size_t)b * N_GEN + t) * F_GEN);

    // 16 float4 loads total; unroll-by-4 keeps <= ~8 float4 live at once.
    #pragma unroll 4
    for (int ff = 0; ff < F_GEN / 4; ++ff) {
        const float4 v = xr[ff];
        const float xv[4] = {v.x, v.y, v.z, v.w};
        #pragma unroll
        for (int c = 0; c < 4; ++c) {
            // Wg row is wave-uniform -> scalar loads, FMA takes SGPR operand
            const float* __restrict__ wrow = Wg + (ff * 4 + c) * EMB;
            #pragma unroll
            for (int e = 0; e < EMB; ++e)
                acc[e] = fmaf(xv[c], wrow[e], acc[e]);
        }
    }

    // ---- value head partial: sum_e relu(acc[e]) * Wv[n*16+e] ----
    const float4* __restrict__ wv4 =
        reinterpret_cast<const float4*>(Wv + (size_t)t * EMB);
    float vp = 0.0f;
    #pragma unroll
    for (int q = 0; q < EMB / 4; ++q) {
        const float4 w = wv4[q];
        vp = fmaf(fmaxf(acc[q * 4 + 0], 0.0f), w.x, vp);
        vp = fmaf(fmaxf(acc[q * 4 + 1], 0.0f), w.y, vp);
        vp = fmaf(fmaxf(acc[q * 4 + 2], 0.0f), w.z, vp);
        vp = fmaf(fmaxf(acc[q * 4 + 3], 0.0f), w.w, vp);
    }

    // ---- block reduction over 512 threads (8 waves of 64) ----
    #pragma unroll
    for (int off = 32; off > 0; off >>= 1)
        vp += __shfl_down(vp, off, 64);

    __shared__ float red[8];
    const int wave = t >> 6;
    const int lane = t & 63;
    if (lane == 0) red[wave] = vp;
    __syncthreads();
    if (t == 0) {
        float s = 0.0f;
        #pragma unroll
        for (int w = 0; w < 8; ++w) s += red[w];
        orow[2 * N_GEN] = s + bv[0];   // val goes in the last column
    }
}

extern "C" void kernel_launch(void* const* d_in, const int* in_sizes, int n_in,
                              void* d_out, int out_size, void* d_ws, size_t ws_size,
                              hipStream_t stream) {
    const float* x     = (const float*)d_in[0];  // [B, N, F]
    const float* Wg    = (const float*)d_in[1];  // [F, E]
    const float* bg    = (const float*)d_in[2];  // [E]
    const float* Wv    = (const float*)d_in[3];  // [N*E, 1]
    const float* bv    = (const float*)d_in[4];  // [1]
    const float* param = (const float*)d_in[5];  // [2]
    const float* high  = (const float*)d_in[6];  // [N]
    float* out = (float*)d_out;                  // [B, 2N+1]

    const int B = in_sizes[0] / (N_GEN * F_GEN); // 4096

    fused_policy_value_kernel<<<B, N_GEN, 0, stream>>>(
        x, Wg, bg, Wv, bv, param, high, out);
}